// Round 2
// baseline (57.768 us; speedup 1.0000x reference)
//
#include <hip/hip_runtime.h>

// MTGP covariance: cov[i,j] = sum_z W[ti,z]W[tj,z]*th[z,0]*exp(-0.5*th[z,1]*||Xi-Xj||^2) + 0.002*I
// M=4096, D=64, Z=4, fp32. Triangular wave-tiles: each wave = 64 rows (lane=row) x 32 cols.
// Dot products from per-lane register row (64 VGPR) x LDS-broadcast B row. No __syncthreads.

#define M_PTS 4096
#define DIM   64
#define JITTER_F 0.002f
#define NEG_HALF_LOG2E (-0.72134752044448170f)  // -0.5*log2(e)
#define WPB   4
#define TPB   256
#define NITEMS 4160        // sum_{I=0..63} (128 - 2I)
#define NBLK  (NITEMS / WPB)
// per-wave LDS floats: Bs 32x64=2048 | BsSq 32 | BsT 4x68=272
#define WLDS  2352

__device__ __forceinline__ float fast_exp2(float x) {
#if defined(__has_builtin)
#if __has_builtin(__builtin_amdgcn_exp2f)
  return __builtin_amdgcn_exp2f(x);
#else
  return exp2f(x);
#endif
#else
  return exp2f(x);
#endif
}

// swizzled B tile: row j, float4-slot s stored at slot (s ^ (j&15))
__device__ __forceinline__ float4 ldsB4(const float* BsW, int j, int s) {
  return *(const float4*)&BsW[(j << 6) + (((s) ^ (j & 15)) << 2)];
}

#define FMA4(p, bv, av) { \
  p = fmaf((bv).x, (av).x, p); \
  p = fmaf((bv).y, (av).y, p); \
  p = fmaf((bv).z, (av).z, p); \
  p = fmaf((bv).w, (av).w, p); }

#define CHUNK_PF(B, pj, pc) { \
  B[0] = ldsB4(BsW, (pj), (pc)*4 + 0); \
  B[1] = ldsB4(BsW, (pj), (pc)*4 + 1); \
  B[2] = ldsB4(BsW, (pj), (pc)*4 + 2); \
  B[3] = ldsB4(BsW, (pj), (pc)*4 + 3); }

#define CHUNK_FMA(B, c) { \
  FMA4(p0, B[0], a[(c)*4 + 0]) \
  FMA4(p0, B[1], a[(c)*4 + 1]) \
  FMA4(p1, B[2], a[(c)*4 + 2]) \
  FMA4(p1, B[3], a[(c)*4 + 3]) }

#define JJ_BODY(jjv, CVF) { \
  const int j = jb4 + (jjv); \
  const float sqbj = BsSq[j]; \
  float p0 = 0.0f, p1 = 0.0f; \
  CHUNK_PF(bw1, j, 1) CHUNK_FMA(bw0, 0) \
  CHUNK_PF(bw0, j, 2) CHUNK_FMA(bw1, 1) \
  CHUNK_PF(bw1, j, 3) CHUNK_FMA(bw0, 2) \
  CHUNK_PF(bw0, j + 1, 0) CHUNK_FMA(bw1, 3) \
  const float d = p0 + p1; \
  const float sd = fmaxf(fmaf(-2.0f, d, sqa + sqbj), 0.0f); \
  float v = cz.x * fast_exp2(ez.x * sd); \
  v = fmaf(cz.y, fast_exp2(ez.y * sd), v); \
  v = fmaf(cz.z, fast_exp2(ez.z * sd), v); \
  v = fmaf(cz.w, fast_exp2(ez.w * sd), v); \
  if (row_i == gj0 + j) v += JITTER_F; \
  cv.CVF = v; \
  BsT[(jjv)*68 + lane] = v; \
}

__global__ __launch_bounds__(TPB, 4) void mtgp_cov(
    const float* __restrict__ X,      // [4096,64]
    const float* __restrict__ W,      // [4,4]
    const float* __restrict__ theta,  // [4,2]
    float* __restrict__ out) {        // [4096,4096]
  __shared__ float lds[WPB * WLDS];
  const int lane = threadIdx.x & 63;
  const int wid  = threadIdx.x >> 6;
  float* BsW  = lds + wid * WLDS;
  float* BsSq = BsW + 2048;
  float* BsT  = BsW + 2080;

  // ---- decode wave item -> (I, Jc), prefix(I) = I*(129-I) ----
  const int item = blockIdx.x * WPB + wid;
  int I;
  {
    const float fd = 16641.0f - 4.0f * (float)item;
    I = (int)((129.0f - sqrtf(fd)) * 0.5f);
    if (I < 0) I = 0;
    if (I > 63) I = 63;
    while (I > 0 && I * (129 - I) > item) --I;
    while ((I + 1) * (129 - (I + 1)) <= item) ++I;
  }
  const int rem = item - I * (129 - I);
  const int Jc  = 2 * I + rem;          // column chunk (32 cols each), Jc >= 2I
  const int gi0 = I << 6;
  const int gj0 = Jc << 5;
  const int row_i = gi0 + lane;

  // ---- A row -> 64 VGPRs (issued early; latency hides under B staging) ----
  float4 a[16];
  {
    const float4* ar = (const float4*)(X + (size_t)row_i * DIM);
#pragma unroll
    for (int s = 0; s < 16; ++s) a[s] = ar[s];
  }

  // ---- B staging: lanes 0..31 own row gj0+lane (swizzled) + row norm ----
  if (lane < 32) {
    const float4* br = (const float4*)(X + (size_t)(gj0 + lane) * DIM);
    float sq = 0.0f;
    const int sw = lane & 15;
#pragma unroll 1
    for (int cs = 0; cs < 4; ++cs) {
      float4 b0 = br[cs*4+0], b1 = br[cs*4+1], b2 = br[cs*4+2], b3 = br[cs*4+3];
      FMA4(sq, b0, b0) FMA4(sq, b1, b1) FMA4(sq, b2, b2) FMA4(sq, b3, b3)
      *(float4*)&BsW[(lane << 6) + (((cs*4+0) ^ sw) << 2)] = b0;
      *(float4*)&BsW[(lane << 6) + (((cs*4+1) ^ sw) << 2)] = b1;
      *(float4*)&BsW[(lane << 6) + (((cs*4+2) ^ sw) << 2)] = b2;
      *(float4*)&BsW[(lane << 6) + (((cs*4+3) ^ sw) << 2)] = b3;
    }
    BsSq[lane] = sq;
  }

  // ---- own-row norm (same ascending FMA order as staged norms: bitwise symmetric) ----
  float sqa = 0.0f;
#pragma unroll
  for (int s = 0; s < 16; ++s) FMA4(sqa, a[s], a[s])

  // ---- mixing coefficients ----
  const int ti = gi0 >> 10, tj = gj0 >> 10;
  float4 cz, ez;
  cz.x = W[ti*4+0] * W[tj*4+0] * theta[0]; ez.x = NEG_HALF_LOG2E * theta[1];
  cz.y = W[ti*4+1] * W[tj*4+1] * theta[2]; ez.y = NEG_HALF_LOG2E * theta[3];
  cz.z = W[ti*4+2] * W[tj*4+2] * theta[4]; ez.z = NEG_HALF_LOG2E * theta[5];
  cz.w = W[ti*4+3] * W[tj*4+3] * theta[6]; ez.w = NEG_HALF_LOG2E * theta[7];

  // staging writes must land before broadcast reads (same wave, DS in-order + drain)
  asm volatile("s_waitcnt lgkmcnt(0)" ::: "memory");

  // ---- j-loop: depth-1 double-buffered broadcast chunks ----
  float4 bw0[4], bw1[4];
  CHUNK_PF(bw0, 0, 0)

  float* orow = out + (size_t)row_i * M_PTS + gj0;

#pragma unroll 1
  for (int jb = 0; jb < 8; ++jb) {
    const int jb4 = jb << 2;
    float4 cv;
    JJ_BODY(0, x)
    JJ_BODY(1, y)
    JJ_BODY(2, z)
    JJ_BODY(3, w)
    // direct orientation: lane's row, 4 cols (scattered float4; lines filled by Jc-neighbors)
    *(float4*)&orow[jb4] = cv;
    // transposed orientation: coalesced via per-wave 4x68 LDS transpose
    asm volatile("s_waitcnt lgkmcnt(0)" ::: "memory");
    const int r = lane >> 4, q = lane & 15;
    const float4 t4 = *(const float4*)&BsT[r * 68 + (q << 2)];
    *(float4*)&out[(size_t)(gj0 + jb4 + r) * M_PTS + gi0 + (q << 2)] = t4;
  }
}

extern "C" void kernel_launch(void* const* d_in, const int* in_sizes, int n_in,
                              void* d_out, int out_size, void* d_ws, size_t ws_size,
                              hipStream_t stream) {
  const float* x     = (const float*)d_in[0];   // (4,1024,64)
  const float* W     = (const float*)d_in[1];   // (4,4)
  const float* theta = (const float*)d_in[2];   // (4,2)
  float* out = (float*)d_out;                   // (4096,4096)

  mtgp_cov<<<dim3(NBLK), dim3(TPB), 0, stream>>>(x, W, theta, out);
}

// Round 3
// 39.657 us; speedup vs baseline: 1.4567x; 1.4567x over previous
//
#include <hip/hip_runtime.h>

// MTGP covariance via bf16 hi/lo-split MFMA.
// cov[i,j] = sum_z W[ti,z]W[tj,z]*th[z,0]*exp(-0.5*th[z,1]*||Xi-Xj||^2) + 0.002*I
// M=4096, D=64, Z=4, fp32 in/out.
// Kernel 1 (prep): X -> Xhi,Xlo (bf16 rne split) + row norms sq, into d_ws.
// Kernel 2 (main): 2080 one-wave blocks, each computes a 64x64 tile of the
// upper triangle with 16x16x32 bf16 MFMA (hh+hl+lh), fused RBF epilogue,
// stores tile and (off-diag only) its transpose. No LDS, no barriers.

#define M_PTS 4096
#define DIM 64
#define JITTER_F 0.002f
#define NEG_HALF_LOG2E (-0.72134752044448170f)  // -0.5*log2(e)

typedef __attribute__((ext_vector_type(8))) short short8v;   // 8 bf16
typedef __attribute__((ext_vector_type(4))) float f32x4;

union FragU { short8v v; uint2 h[2]; };

__device__ __forceinline__ float fast_exp2(float x) {
#if defined(__has_builtin)
#if __has_builtin(__builtin_amdgcn_exp2f)
  return __builtin_amdgcn_exp2f(x);
#else
  return exp2f(x);
#endif
#else
  return exp2f(x);
#endif
}

__device__ __forceinline__ unsigned bfr(float x) {  // fp32 -> bf16 (rne), as u16
  unsigned u = __float_as_uint(x);
  return (u + 0x7FFFu + ((u >> 16) & 1u)) >> 16;
}
__device__ __forceinline__ float bff(unsigned h) {  // bf16 bits -> fp32
  return __uint_as_float(h << 16);
}

// ---------------- prep: hi/lo split + row norms ----------------
__global__ __launch_bounds__(256) void mtgp_prep(
    const float* __restrict__ X, unsigned short* __restrict__ Xhi,
    unsigned short* __restrict__ Xlo, float* __restrict__ sqn) {
  const int row = blockIdx.x * 256 + threadIdx.x;  // 0..4095
  const float4* xr = (const float4*)(X + (size_t)row * DIM);
  unsigned* hp = (unsigned*)(Xhi + (size_t)row * DIM);
  unsigned* lp = (unsigned*)(Xlo + (size_t)row * DIM);
  float s = 0.0f;
#define CVT2(xa, xb, oidx) { \
    unsigned ha = bfr(xa), hb = bfr(xb); \
    hp[oidx] = ha | (hb << 16); \
    unsigned la = bfr((xa) - bff(ha)), lb = bfr((xb) - bff(hb)); \
    lp[oidx] = la | (lb << 16); \
    s = fmaf((xa), (xa), s); s = fmaf((xb), (xb), s); }
#pragma unroll
  for (int i = 0; i < 16; ++i) {
    float4 vv = xr[i];
    CVT2(vv.x, vv.y, 2 * i)
    CVT2(vv.z, vv.w, 2 * i + 1)
  }
#undef CVT2
  sqn[row] = s;
}

// ---------------- main: one wave = one 64x64 upper-tri tile ----------------
__global__ __launch_bounds__(64) void mtgp_main(
    const unsigned short* __restrict__ Xhi, const unsigned short* __restrict__ Xlo,
    const float* __restrict__ sqn, const float* __restrict__ W,
    const float* __restrict__ theta, float* __restrict__ out) {
  // decode item -> (u, v), v >= u, 64 slabs; prefix(u) = u*(129-u)/2
  const int item = blockIdx.x;
  int u = (int)((129.0f - sqrtf((float)(16641 - 8 * item))) * 0.5f);
  if (u < 0) u = 0;
  if (u > 63) u = 63;
  while (u > 0 && u * (129 - u) / 2 > item) --u;
  while (u < 63 && (u + 1) * (128 - u) / 2 <= item) ++u;
  const int v = u + (item - u * (129 - u) / 2);
  const int gi0 = u << 6, gj0 = v << 6;

  const int lane = threadIdx.x & 63;
  const int r16 = lane & 15;   // row (A) / col (B) within 16-slab
  const int kg = lane >> 4;    // k-group
  const int kg4 = kg << 2;

  f32x4 acc[4][4];
#pragma unroll
  for (int p = 0; p < 4; ++p)
#pragma unroll
    for (int q = 0; q < 4; ++q) acc[p][q] = (f32x4)0.0f;

#pragma unroll
  for (int k0 = 0; k0 < 2; ++k0) {
    const int oe = k0 * 32 + kg4;  // ushort offset of low k-half for this lane
    FragU ah[4], al[4], bh[4], bl[4];
#pragma unroll
    for (int p = 0; p < 4; ++p) {
      const unsigned short* rah = Xhi + (size_t)(gi0 + p * 16 + r16) * DIM;
      const unsigned short* ral = Xlo + (size_t)(gi0 + p * 16 + r16) * DIM;
      const unsigned short* rbh = Xhi + (size_t)(gj0 + p * 16 + r16) * DIM;
      const unsigned short* rbl = Xlo + (size_t)(gj0 + p * 16 + r16) * DIM;
      ah[p].h[0] = *(const uint2*)&rah[oe];
      ah[p].h[1] = *(const uint2*)&rah[oe + 16];
      al[p].h[0] = *(const uint2*)&ral[oe];
      al[p].h[1] = *(const uint2*)&ral[oe + 16];
      bh[p].h[0] = *(const uint2*)&rbh[oe];
      bh[p].h[1] = *(const uint2*)&rbh[oe + 16];
      bl[p].h[0] = *(const uint2*)&rbl[oe];
      bl[p].h[1] = *(const uint2*)&rbl[oe + 16];
    }
#pragma unroll
    for (int p = 0; p < 4; ++p)
#pragma unroll
      for (int q = 0; q < 4; ++q) {
        acc[p][q] = __builtin_amdgcn_mfma_f32_16x16x32_bf16(ah[p].v, bh[q].v, acc[p][q], 0, 0, 0);
        acc[p][q] = __builtin_amdgcn_mfma_f32_16x16x32_bf16(ah[p].v, bl[q].v, acc[p][q], 0, 0, 0);
        acc[p][q] = __builtin_amdgcn_mfma_f32_16x16x32_bf16(al[p].v, bh[q].v, acc[p][q], 0, 0, 0);
      }
  }

  // ---- epilogue: sd = max(sq_i + sq_j - 2*dot, 0); v = sum_z cz*exp2(ez*sd) ----
  const int ti = u >> 4, tj = v >> 4;  // 16 slabs of 64 rows per task
  float czv[4], ezv[4];
#pragma unroll
  for (int z = 0; z < 4; ++z) {
    czv[z] = W[ti * 4 + z] * W[tj * 4 + z] * theta[2 * z];
    ezv[z] = NEG_HALF_LOG2E * theta[2 * z + 1];
  }
  f32x4 sqr[4];
  float sqc[4];
#pragma unroll
  for (int p = 0; p < 4; ++p) sqr[p] = *(const f32x4*)&sqn[gi0 + p * 16 + kg4];
#pragma unroll
  for (int q = 0; q < 4; ++q) sqc[q] = sqn[gj0 + q * 16 + r16];

#pragma unroll
  for (int p = 0; p < 4; ++p)
#pragma unroll
    for (int q = 0; q < 4; ++q)
#pragma unroll
      for (int r = 0; r < 4; ++r) {
        const float d = acc[p][q][r];
        const float sd = fmaxf(fmaf(-2.0f, d, sqr[p][r] + sqc[q]), 0.0f);
        float val = czv[0] * fast_exp2(ezv[0] * sd);
        val = fmaf(czv[1], fast_exp2(ezv[1] * sd), val);
        val = fmaf(czv[2], fast_exp2(ezv[2] * sd), val);
        val = fmaf(czv[3], fast_exp2(ezv[3] * sd), val);
        acc[p][q][r] = val;
      }

  if (u == v) {  // jitter on global diagonal (C/D: row = kg*4+r, col = r16)
#pragma unroll
    for (int p = 0; p < 4; ++p)
#pragma unroll
      for (int r = 0; r < 4; ++r)
        if (kg4 + r == r16) acc[p][p][r] += JITTER_F;
  }

  // ---- stores: direct (rows gi0.., cols gj0..) ----
#pragma unroll
  for (int p = 0; p < 4; ++p)
#pragma unroll
    for (int r = 0; r < 4; ++r) {
      float* rp = out + (size_t)(gi0 + p * 16 + kg4 + r) * M_PTS + gj0 + r16;
      rp[0]  = acc[p][0][r];
      rp[16] = acc[p][1][r];
      rp[32] = acc[p][2][r];
      rp[48] = acc[p][3][r];
    }
  // ---- transposed (off-diagonal only; disjoint region, coalesced float4) ----
  if (u != v) {
#pragma unroll
    for (int q = 0; q < 4; ++q)
#pragma unroll
      for (int p = 0; p < 4; ++p) {
        f32x4* tp = (f32x4*)(out + (size_t)(gj0 + q * 16 + r16) * M_PTS + gi0 + p * 16 + kg4);
        *tp = acc[p][q];
      }
  }
}

extern "C" void kernel_launch(void* const* d_in, const int* in_sizes, int n_in,
                              void* d_out, int out_size, void* d_ws, size_t ws_size,
                              hipStream_t stream) {
  const float* x     = (const float*)d_in[0];   // (4,1024,64)
  const float* W     = (const float*)d_in[1];   // (4,4)
  const float* theta = (const float*)d_in[2];   // (4,2)
  float* out = (float*)d_out;                   // (4096,4096)

  // workspace layout: sq (16 KB) | Xhi (512 KB) | Xlo (512 KB)
  float* sqn = (float*)d_ws;
  unsigned short* Xhi = (unsigned short*)((char*)d_ws + 16384);
  unsigned short* Xlo = (unsigned short*)((char*)d_ws + 16384 + 524288);

  mtgp_prep<<<dim3(M_PTS / 256), dim3(256), 0, stream>>>(x, Xhi, Xlo, sqn);
  mtgp_main<<<dim3(2080), dim3(64), 0, stream>>>(Xhi, Xlo, sqn, W, theta, out);
}